// Round 16
// baseline (152.524 us; speedup 1.0000x reference)
//
#include <hip/hip_runtime.h>

#define IN_CH  64
#define OUT_CH 32
#define BLOCK  8

using short8 = __attribute__((ext_vector_type(8))) short;
using f32x4v = __attribute__((ext_vector_type(4))) float;

// ws layout: argmax M*4 only.
// R16 = R15 verbatim + 2 extra k_compute launches (idempotent) as a timing
// probe: delta_total = 2 x compute marginal cost. Decides whether the ~50us
// budget gap lives in compute or in the scatter passes.

__global__ void k_prep(int4* __restrict__ argmax4, int n4) {
    int i = blockIdx.x * 256 + threadIdx.x;
    if (i < n4) argmax4[i] = make_int4(-1, -1, -1, -1);
}

// argmax[m] monotone non-decreasing => stale read is a valid lower bound;
// filtered atomicMax is always correct. Dispatch split makes pass-1 winners
// visible so pass-2 filters ~88% of its atomics.
__global__ void k_scatter7(const int* __restrict__ pair, int* __restrict__ argmax, int N) {
    int i = blockIdx.x * 256 + threadIdx.x;
    if (i >= N) return;
    int n = N - 1 - i;                 // descending: high-t first
    int t = 7 * N + n;
    int m = pair[t];
    if (m >= 0 && argmax[m] < t) atomicMax(&argmax[m], t);
}

__global__ void k_scatter_rest(const int* __restrict__ pair, int* __restrict__ argmax, int N) {
    int n = blockIdx.x * 256 + threadIdx.x;
    if (n >= N) return;
    for (int j = 6; j >= 0; --j) {
        int t = j * N + n;
        int m = pair[t];
        if (m >= 0 && argmax[m] < t) atomicMax(&argmax[m], t);
    }
}

__device__ __forceinline__ unsigned cvt_pk_bf16(float lo, float hi) {
    unsigned r;
    asm("v_cvt_pk_bf16_f32 %0, %1, %2" : "=v"(r) : "v"(lo), "v"(hi));
    return r;
}

__device__ __forceinline__ short8 pack8(float4 a, float4 b) {
    union { unsigned u[4]; short8 s; } p;
    p.u[0] = cvt_pk_bf16(a.x, a.y);
    p.u[1] = cvt_pk_bf16(a.z, a.w);
    p.u[2] = cvt_pk_bf16(b.x, b.y);
    p.u[3] = cvt_pk_bf16(b.z, b.w);
    return p.s;
}

// m-ordered masked MFMA, fill-free (R15 structure, unchanged).
__global__ __launch_bounds__(256, 3) void k_compute(
        const float* __restrict__ x, const float* __restrict__ w,
        const int* __restrict__ argmax, float* __restrict__ out,
        int M, int N) {
    const int lane = threadIdx.x & 63;
    const int r16  = lane & 15;
    const int kc   = lane >> 4;
    const int wv   = threadIdx.x >> 6;

    int base = (blockIdx.x * 4 + wv) * 64;
    if (base >= M) return;                 // M % 64 == 0: no row tails

    int t_[4];
#pragma unroll
    for (int st = 0; st < 4; ++st)
        t_[st] = argmax[base + st * 16 + r16];
    const int N1 = N, N2 = 2 * N, N4 = 4 * N;
    int j_[4], n_[4];
#pragma unroll
    for (int st = 0; st < 4; ++st) {
        int v = t_[st], j = 0;
        if (v >= N4) { j = 4;  v -= N4; }
        if (v >= N2) { j += 2; v -= N2; }
        if (v >= N1) { j += 1; v -= N1; }
        bool ok = t_[st] >= 0;
        j_[st] = ok ? j : 8;               // 8 = unmapped sentinel
        n_[st] = ok ? v : 0;
    }

    short8 bf7[2][2];
#pragma unroll
    for (int ot = 0; ot < 2; ++ot)
#pragma unroll
        for (int kk = 0; kk < 2; ++kk) {
            const float* wp = w + ((ot * 16 + r16) * BLOCK + 7) * IN_CH + kk * 32 + kc * 8;
            bf7[ot][kk] = pack8(*(const float4*)wp, *(const float4*)(wp + 4));
        }

    float4 xs[2][4];
    {
        const float* xp = x + (size_t)n_[0] * IN_CH + kc * 8;
        xs[0][0] = *(const float4*)xp;        xs[0][1] = *(const float4*)(xp + 4);
        xs[0][2] = *(const float4*)(xp + 32); xs[0][3] = *(const float4*)(xp + 36);
    }

#pragma unroll
    for (int st = 0; st < 4; ++st) {
        const int cur = st & 1;
        if (st < 3) {
            const float* xp = x + (size_t)n_[st + 1] * IN_CH + kc * 8;
            xs[cur ^ 1][0] = *(const float4*)xp;        xs[cur ^ 1][1] = *(const float4*)(xp + 4);
            xs[cur ^ 1][2] = *(const float4*)(xp + 32); xs[cur ^ 1][3] = *(const float4*)(xp + 36);
        }

        short8 a0 = pack8(xs[cur][0], xs[cur][1]);   // k 0..31
        short8 a1 = pack8(xs[cur][2], xs[cur][3]);   // k 32..63
        const int jr = j_[st];
        const short8 zz = (short8)0;

        f32x4v acc0 = {0.f, 0.f, 0.f, 0.f};
        f32x4v acc1 = {0.f, 0.f, 0.f, 0.f};
#pragma unroll
        for (int j = 0; j < 8; ++j) {
            bool pj = (jr == j);
            if (__ballot(pj) == 0ull) continue;      // skip absent j's
            short8 m0 = pj ? a0 : zz;
            short8 m1 = pj ? a1 : zz;
            short8 b00, b01, b10, b11;
            if (j == 7) {
                b00 = bf7[0][0]; b01 = bf7[0][1];
                b10 = bf7[1][0]; b11 = bf7[1][1];
            } else {
                const float* wp0 = w + ((r16)      * BLOCK + j) * IN_CH + kc * 8;
                const float* wp1 = w + ((16 + r16) * BLOCK + j) * IN_CH + kc * 8;
                b00 = pack8(*(const float4*)wp0,        *(const float4*)(wp0 + 4));
                b01 = pack8(*(const float4*)(wp0 + 32), *(const float4*)(wp0 + 36));
                b10 = pack8(*(const float4*)wp1,        *(const float4*)(wp1 + 4));
                b11 = pack8(*(const float4*)(wp1 + 32), *(const float4*)(wp1 + 36));
            }
            acc0 = __builtin_amdgcn_mfma_f32_16x16x32_bf16(m0, b00, acc0, 0, 0, 0);
            acc0 = __builtin_amdgcn_mfma_f32_16x16x32_bf16(m1, b01, acc0, 0, 0, 0);
            acc1 = __builtin_amdgcn_mfma_f32_16x16x32_bf16(m0, b10, acc1, 0, 0, 0);
            acc1 = __builtin_amdgcn_mfma_f32_16x16x32_bf16(m1, b11, acc1, 0, 0, 0);
        }

#pragma unroll
        for (int q = 0; q < 4; ++q) {
            size_t ro = (size_t)(base + st * 16 + kc * 4 + q) * OUT_CH;
            out[ro + r16]      = acc0[q];
            out[ro + 16 + r16] = acc1[q];
        }
    }
}

extern "C" void kernel_launch(void* const* d_in, const int* in_sizes, int n_in,
                              void* d_out, int out_size, void* d_ws, size_t ws_size,
                              hipStream_t stream) {
    const float* x    = (const float*)d_in[0];
    const float* w    = (const float*)d_in[1];
    const int*   pair = (const int*)d_in[2];
    int N = in_sizes[0] / IN_CH;     // 400000
    int M = out_size / OUT_CH;       // 200000

    int* argmax = (int*)d_ws;

    int n4 = M / 4;                  // M % 4 == 0
    k_prep<<<(n4 + 255) / 256, 256, 0, stream>>>((int4*)argmax, n4);

    int gN = (N + 255) / 256;
    k_scatter7    <<<gN, 256, 0, stream>>>(pair, argmax, N);   // j=7, high-t first
    k_scatter_rest<<<gN, 256, 0, stream>>>(pair, argmax, N);   // j=6..0, filtered

    int tiles  = M / 64;             // 3125
    int blocks = (tiles + 3) / 4;    // 782, whole grid co-resident
    // TIMING PROBE: 3 identical compute launches (idempotent).
    // delta vs R15 = 2 x compute marginal cost.
    k_compute<<<blocks, 256, 0, stream>>>(x, w, argmax, (float*)d_out, M, N);
    k_compute<<<blocks, 256, 0, stream>>>(x, w, argmax, (float*)d_out, M, N);
    k_compute<<<blocks, 256, 0, stream>>>(x, w, argmax, (float*)d_out, M, N);
}

// Round 17
// 107.137 us; speedup vs baseline: 1.4236x; 1.4236x over previous
//
#include <hip/hip_runtime.h>

#define IN_CH  64
#define OUT_CH 32
#define BLOCK  8

using short8 = __attribute__((ext_vector_type(8))) short;
using f32x4v = __attribute__((ext_vector_type(4))) float;

// ws layout: argmax M*4 only.
// R16 probe: compute marginal ~31us, non-compute ~55-59us. This round:
// (1) compute x-gather 4-deep upfront (serial latency ~3 -> ~1);
// (2) scatter_rest: batch 7 pair loads + 7 filter reads (chain 7 -> ~2).

__global__ void k_prep(int4* __restrict__ argmax4, int n4) {
    int i = blockIdx.x * 256 + threadIdx.x;
    if (i < n4) argmax4[i] = make_int4(-1, -1, -1, -1);
}

// argmax[m] monotone non-decreasing => stale read is a valid lower bound;
// filtered atomicMax is always correct. Dispatch split makes pass-1 winners
// visible so pass-2 filters ~88% of its atomics.
__global__ void k_scatter7(const int* __restrict__ pair, int* __restrict__ argmax, int N) {
    int i = blockIdx.x * 256 + threadIdx.x;
    if (i >= N) return;
    int n = N - 1 - i;                 // descending: high-t first
    int t = 7 * N + n;
    int m = pair[t];
    if (m >= 0 && argmax[m] < t) atomicMax(&argmax[m], t);
}

__global__ void k_scatter_rest(const int* __restrict__ pair, int* __restrict__ argmax, int N) {
    int n = blockIdx.x * 256 + threadIdx.x;
    if (n >= N) return;
    // batch phase 1: 7 independent coalesced pair reads
    int mv[7];
#pragma unroll
    for (int j = 6; j >= 0; --j) mv[6 - j] = pair[j * N + n];
    // batch phase 2: 7 independent random filter reads (stale-safe)
    int av[7];
#pragma unroll
    for (int i7 = 0; i7 < 7; ++i7) av[i7] = (mv[i7] >= 0) ? argmax[mv[i7]] : 0x7fffffff;
    // phase 3: surviving atomics (hi j first -- bigger t wins more)
#pragma unroll
    for (int i7 = 0; i7 < 7; ++i7) {
        int t = (6 - i7) * N + n;
        if (mv[i7] >= 0 && av[i7] < t) atomicMax(&argmax[mv[i7]], t);
    }
}

__device__ __forceinline__ unsigned cvt_pk_bf16(float lo, float hi) {
    unsigned r;
    asm("v_cvt_pk_bf16_f32 %0, %1, %2" : "=v"(r) : "v"(lo), "v"(hi));
    return r;
}

__device__ __forceinline__ short8 pack8(float4 a, float4 b) {
    union { unsigned u[4]; short8 s; } p;
    p.u[0] = cvt_pk_bf16(a.x, a.y);
    p.u[1] = cvt_pk_bf16(a.z, a.w);
    p.u[2] = cvt_pk_bf16(b.x, b.y);
    p.u[3] = cvt_pk_bf16(b.z, b.w);
    return p.s;
}

// m-ordered masked MFMA, fill-free; x-gather for ALL 4 subtiles issued
// upfront (16 independent 16B loads/lane) so the wave pays ~1 gather
// latency instead of ~3. VGPR ~160 -> still 3 waves/SIMD.
__global__ __launch_bounds__(256, 3) void k_compute(
        const float* __restrict__ x, const float* __restrict__ w,
        const int* __restrict__ argmax, float* __restrict__ out,
        int M, int N) {
    const int lane = threadIdx.x & 63;
    const int r16  = lane & 15;
    const int kc   = lane >> 4;
    const int wv   = threadIdx.x >> 6;

    int base = (blockIdx.x * 4 + wv) * 64;
    if (base >= M) return;                 // M % 64 == 0: no row tails

    // metadata: 4 independent coalesced loads, branch-free decode
    int t_[4];
#pragma unroll
    for (int st = 0; st < 4; ++st)
        t_[st] = argmax[base + st * 16 + r16];
    const int N1 = N, N2 = 2 * N, N4 = 4 * N;
    int j_[4], n_[4];
#pragma unroll
    for (int st = 0; st < 4; ++st) {
        int v = t_[st], j = 0;
        if (v >= N4) { j = 4;  v -= N4; }
        if (v >= N2) { j += 2; v -= N2; }
        if (v >= N1) { j += 1; v -= N1; }
        bool ok = t_[st] >= 0;
        j_[st] = ok ? j : 8;               // 8 = unmapped sentinel
        n_[st] = ok ? v : 0;
    }

    // x gather: ALL 4 subtiles upfront -- 16 independent loads in flight
    float4 xs[4][4];
#pragma unroll
    for (int st = 0; st < 4; ++st) {
        const float* xp = x + (size_t)n_[st] * IN_CH + kc * 8;
        xs[st][0] = *(const float4*)xp;
        xs[st][1] = *(const float4*)(xp + 4);
        xs[st][2] = *(const float4*)(xp + 32);
        xs[st][3] = *(const float4*)(xp + 36);
    }

    // resident B for dominant j=7
    short8 bf7[2][2];
#pragma unroll
    for (int ot = 0; ot < 2; ++ot)
#pragma unroll
        for (int kk = 0; kk < 2; ++kk) {
            const float* wp = w + ((ot * 16 + r16) * BLOCK + 7) * IN_CH + kk * 32 + kc * 8;
            bf7[ot][kk] = pack8(*(const float4*)wp, *(const float4*)(wp + 4));
        }

#pragma unroll
    for (int st = 0; st < 4; ++st) {
        short8 a0 = pack8(xs[st][0], xs[st][1]);   // k 0..31
        short8 a1 = pack8(xs[st][2], xs[st][3]);   // k 32..63
        const int jr = j_[st];
        const short8 zz = (short8)0;

        f32x4v acc0 = {0.f, 0.f, 0.f, 0.f};
        f32x4v acc1 = {0.f, 0.f, 0.f, 0.f};
#pragma unroll
        for (int j = 0; j < 8; ++j) {
            bool pj = (jr == j);
            if (__ballot(pj) == 0ull) continue;    // skip absent j's
            short8 m0 = pj ? a0 : zz;
            short8 m1 = pj ? a1 : zz;
            short8 b00, b01, b10, b11;
            if (j == 7) {
                b00 = bf7[0][0]; b01 = bf7[0][1];
                b10 = bf7[1][0]; b11 = bf7[1][1];
            } else {
                const float* wp0 = w + ((r16)      * BLOCK + j) * IN_CH + kc * 8;
                const float* wp1 = w + ((16 + r16) * BLOCK + j) * IN_CH + kc * 8;
                b00 = pack8(*(const float4*)wp0,        *(const float4*)(wp0 + 4));
                b01 = pack8(*(const float4*)(wp0 + 32), *(const float4*)(wp0 + 36));
                b10 = pack8(*(const float4*)wp1,        *(const float4*)(wp1 + 4));
                b11 = pack8(*(const float4*)(wp1 + 32), *(const float4*)(wp1 + 36));
            }
            acc0 = __builtin_amdgcn_mfma_f32_16x16x32_bf16(m0, b00, acc0, 0, 0, 0);
            acc0 = __builtin_amdgcn_mfma_f32_16x16x32_bf16(m1, b01, acc0, 0, 0, 0);
            acc1 = __builtin_amdgcn_mfma_f32_16x16x32_bf16(m0, b10, acc1, 0, 0, 0);
            acc1 = __builtin_amdgcn_mfma_f32_16x16x32_bf16(m1, b11, acc1, 0, 0, 0);
        }

        // dense coalesced stores
#pragma unroll
        for (int q = 0; q < 4; ++q) {
            size_t ro = (size_t)(base + st * 16 + kc * 4 + q) * OUT_CH;
            out[ro + r16]      = acc0[q];
            out[ro + 16 + r16] = acc1[q];
        }
    }
}

extern "C" void kernel_launch(void* const* d_in, const int* in_sizes, int n_in,
                              void* d_out, int out_size, void* d_ws, size_t ws_size,
                              hipStream_t stream) {
    const float* x    = (const float*)d_in[0];
    const float* w    = (const float*)d_in[1];
    const int*   pair = (const int*)d_in[2];
    int N = in_sizes[0] / IN_CH;     // 400000
    int M = out_size / OUT_CH;       // 200000

    int* argmax = (int*)d_ws;

    int n4 = M / 4;                  // M % 4 == 0
    k_prep<<<(n4 + 255) / 256, 256, 0, stream>>>((int4*)argmax, n4);

    int gN = (N + 255) / 256;
    k_scatter7    <<<gN, 256, 0, stream>>>(pair, argmax, N);   // j=7, high-t first
    k_scatter_rest<<<gN, 256, 0, stream>>>(pair, argmax, N);   // j=6..0, filtered

    int tiles  = M / 64;             // 3125
    int blocks = (tiles + 3) / 4;    // 782, whole grid co-resident
    k_compute<<<blocks, 256, 0, stream>>>(x, w, argmax, (float*)d_out, M, N);
}

// Round 18
// 88.214 us; speedup vs baseline: 1.7290x; 1.2145x over previous
//
#include <hip/hip_runtime.h>

#define IN_CH  64
#define OUT_CH 32
#define BLOCK  8

using short8 = __attribute__((ext_vector_type(8))) short;
using f32x4v = __attribute__((ext_vector_type(4))) float;

// ws layout: argmax M*4 | claimed M bytes (L2-resident bytemap).
// R15 compute verbatim (best: 90.0us, ~140 VGPR, no spill).
// Single change vs R15: claimed-bytemap filter for scatter_rest.

__global__ void k_prep(int4* __restrict__ argmax4, int n4, int4* __restrict__ claimed4, int nc4) {
    int i = blockIdx.x * 256 + threadIdx.x;
    if (i < n4) argmax4[i] = make_int4(-1, -1, -1, -1);
    if (i < nc4) claimed4[i] = make_int4(0, 0, 0, 0);
}

// argmax[m] monotone non-decreasing => stale read is a valid lower bound;
// filtered atomicMax is always correct. claimed[m]=1 for EVERY valid j=7
// mapping (benign-race byte store): t=7N+n beats any j<=6 t, so the rest
// pass may skip claimed rows entirely (winner committed at dispatch boundary).
__global__ void k_scatter7(const int* __restrict__ pair, int* __restrict__ argmax,
                           unsigned char* __restrict__ claimed, int N) {
    int i = blockIdx.x * 256 + threadIdx.x;
    if (i >= N) return;
    int n = N - 1 - i;                 // descending: high-t first
    int t = 7 * N + n;
    int m = pair[t];
    if (m >= 0) {
        claimed[m] = 1;
        if (argmax[m] < t) atomicMax(&argmax[m], t);
    }
}

__global__ void k_scatter_rest(const int* __restrict__ pair, int* __restrict__ argmax,
                               const unsigned char* __restrict__ claimed, int N) {
    int n = blockIdx.x * 256 + threadIdx.x;
    if (n >= N) return;
    for (int j = 6; j >= 0; --j) {
        int t = j * N + n;
        int m = pair[t];
        // claimed check: 200KB L2-resident byte read kills ~88% of the
        // random 64B argmax reads and nearly all surviving atomics.
        if (m >= 0 && !claimed[m] && argmax[m] < t)
            atomicMax(&argmax[m], t);
    }
}

__device__ __forceinline__ unsigned cvt_pk_bf16(float lo, float hi) {
    unsigned r;
    asm("v_cvt_pk_bf16_f32 %0, %1, %2" : "=v"(r) : "v"(lo), "v"(hi));
    return r;
}

__device__ __forceinline__ short8 pack8(float4 a, float4 b) {
    union { unsigned u[4]; short8 s; } p;
    p.u[0] = cvt_pk_bf16(a.x, a.y);
    p.u[1] = cvt_pk_bf16(a.z, a.w);
    p.u[2] = cvt_pk_bf16(b.x, b.y);
    p.u[3] = cvt_pk_bf16(b.z, b.w);
    return p.s;
}

// m-ordered masked MFMA, fill-free (R15 structure, unchanged: ping-pong x
// pipeline, ~140 VGPR, 3 waves/SIMD, whole grid co-resident).
__global__ __launch_bounds__(256, 3) void k_compute(
        const float* __restrict__ x, const float* __restrict__ w,
        const int* __restrict__ argmax, float* __restrict__ out,
        int M, int N) {
    const int lane = threadIdx.x & 63;
    const int r16  = lane & 15;
    const int kc   = lane >> 4;
    const int wv   = threadIdx.x >> 6;

    int base = (blockIdx.x * 4 + wv) * 64;
    if (base >= M) return;                 // M % 64 == 0: no row tails

    int t_[4];
#pragma unroll
    for (int st = 0; st < 4; ++st)
        t_[st] = argmax[base + st * 16 + r16];
    const int N1 = N, N2 = 2 * N, N4 = 4 * N;
    int j_[4], n_[4];
#pragma unroll
    for (int st = 0; st < 4; ++st) {
        int v = t_[st], j = 0;
        if (v >= N4) { j = 4;  v -= N4; }
        if (v >= N2) { j += 2; v -= N2; }
        if (v >= N1) { j += 1; v -= N1; }
        bool ok = t_[st] >= 0;
        j_[st] = ok ? j : 8;               // 8 = unmapped sentinel
        n_[st] = ok ? v : 0;
    }

    short8 bf7[2][2];
#pragma unroll
    for (int ot = 0; ot < 2; ++ot)
#pragma unroll
        for (int kk = 0; kk < 2; ++kk) {
            const float* wp = w + ((ot * 16 + r16) * BLOCK + 7) * IN_CH + kk * 32 + kc * 8;
            bf7[ot][kk] = pack8(*(const float4*)wp, *(const float4*)(wp + 4));
        }

    float4 xs[2][4];
    {
        const float* xp = x + (size_t)n_[0] * IN_CH + kc * 8;
        xs[0][0] = *(const float4*)xp;        xs[0][1] = *(const float4*)(xp + 4);
        xs[0][2] = *(const float4*)(xp + 32); xs[0][3] = *(const float4*)(xp + 36);
    }

#pragma unroll
    for (int st = 0; st < 4; ++st) {
        const int cur = st & 1;
        if (st < 3) {
            const float* xp = x + (size_t)n_[st + 1] * IN_CH + kc * 8;
            xs[cur ^ 1][0] = *(const float4*)xp;        xs[cur ^ 1][1] = *(const float4*)(xp + 4);
            xs[cur ^ 1][2] = *(const float4*)(xp + 32); xs[cur ^ 1][3] = *(const float4*)(xp + 36);
        }

        short8 a0 = pack8(xs[cur][0], xs[cur][1]);   // k 0..31
        short8 a1 = pack8(xs[cur][2], xs[cur][3]);   // k 32..63
        const int jr = j_[st];
        const short8 zz = (short8)0;

        f32x4v acc0 = {0.f, 0.f, 0.f, 0.f};
        f32x4v acc1 = {0.f, 0.f, 0.f, 0.f};
#pragma unroll
        for (int j = 0; j < 8; ++j) {
            bool pj = (jr == j);
            if (__ballot(pj) == 0ull) continue;      // skip absent j's
            short8 m0 = pj ? a0 : zz;
            short8 m1 = pj ? a1 : zz;
            short8 b00, b01, b10, b11;
            if (j == 7) {
                b00 = bf7[0][0]; b01 = bf7[0][1];
                b10 = bf7[1][0]; b11 = bf7[1][1];
            } else {
                const float* wp0 = w + ((r16)      * BLOCK + j) * IN_CH + kc * 8;
                const float* wp1 = w + ((16 + r16) * BLOCK + j) * IN_CH + kc * 8;
                b00 = pack8(*(const float4*)wp0,        *(const float4*)(wp0 + 4));
                b01 = pack8(*(const float4*)(wp0 + 32), *(const float4*)(wp0 + 36));
                b10 = pack8(*(const float4*)wp1,        *(const float4*)(wp1 + 4));
                b11 = pack8(*(const float4*)(wp1 + 32), *(const float4*)(wp1 + 36));
            }
            acc0 = __builtin_amdgcn_mfma_f32_16x16x32_bf16(m0, b00, acc0, 0, 0, 0);
            acc0 = __builtin_amdgcn_mfma_f32_16x16x32_bf16(m1, b01, acc0, 0, 0, 0);
            acc1 = __builtin_amdgcn_mfma_f32_16x16x32_bf16(m0, b10, acc1, 0, 0, 0);
            acc1 = __builtin_amdgcn_mfma_f32_16x16x32_bf16(m1, b11, acc1, 0, 0, 0);
        }

#pragma unroll
        for (int q = 0; q < 4; ++q) {
            size_t ro = (size_t)(base + st * 16 + kc * 4 + q) * OUT_CH;
            out[ro + r16]      = acc0[q];
            out[ro + 16 + r16] = acc1[q];
        }
    }
}

extern "C" void kernel_launch(void* const* d_in, const int* in_sizes, int n_in,
                              void* d_out, int out_size, void* d_ws, size_t ws_size,
                              hipStream_t stream) {
    const float* x    = (const float*)d_in[0];
    const float* w    = (const float*)d_in[1];
    const int*   pair = (const int*)d_in[2];
    int N = in_sizes[0] / IN_CH;     // 400000
    int M = out_size / OUT_CH;       // 200000

    int*           argmax  = (int*)d_ws;
    unsigned char* claimed = (unsigned char*)d_ws + (size_t)M * 4;

    int n4  = M / 4;                 // M % 4 == 0
    int nc4 = M / 16;                // claimed bytes as int4
    k_prep<<<(n4 + 255) / 256, 256, 0, stream>>>((int4*)argmax, n4, (int4*)claimed, nc4);

    int gN = (N + 255) / 256;
    k_scatter7    <<<gN, 256, 0, stream>>>(pair, argmax, claimed, N);  // j=7, high-t first
    k_scatter_rest<<<gN, 256, 0, stream>>>(pair, argmax, claimed, N);  // j=6..0, bytemap-filtered

    int tiles  = M / 64;             // 3125
    int blocks = (tiles + 3) / 4;    // 782, whole grid co-resident
    k_compute<<<blocks, 256, 0, stream>>>(x, w, argmax, (float*)d_out, M, N);
}